// Round 9
// baseline (278.147 us; speedup 1.0000x reference)
//
#include <hip/hip_runtime.h>

typedef __bf16 bf16;
typedef __bf16 bf16x4 __attribute__((ext_vector_type(4)));
typedef __bf16 bf16x8 __attribute__((ext_vector_type(8)));
typedef float f32x4 __attribute__((ext_vector_type(4)));

#define MFMA_16x16x32(a, b, c) __builtin_amdgcn_mfma_f32_16x16x32_bf16((a), (b), (c), 0, 0, 0)

#define B_ 8
#define N_ 1024
#define C_ 768
#define H_ 12
#define HD_ 64
#define KDIM 768

__device__ __forceinline__ void gload_lds16(const void* g, void* l) {
  __builtin_amdgcn_global_load_lds(
      (const __attribute__((address_space(1))) void*)g,
      (__attribute__((address_space(3))) void*)l, 16, 0, 0);
}

// ---------------------------------------------------------------------------
// mask dtype detection (robust to int8/int32/int64 storage)
// ---------------------------------------------------------------------------
__global__ __launch_bounds__(256) void detect_mask_kernel(const unsigned* __restrict__ m32,
                                                          int* __restrict__ flags) {
  const int i = blockIdx.x * 256 + threadIdx.x;
  if (i < 2048) {
    const unsigned v = m32[i];
    if (v > 1u) atomicOr(&flags[0], 1);
    if ((i & 1) && v != 0u) atomicOr(&flags[1], 1);
  }
}

// ---------------------------------------------------------------------------
// cvt: f32 -> bf16 for x, w_qkv, w_proj; bias[b*N+n] = mask ? -1e30 : log(size)
// ---------------------------------------------------------------------------
__global__ __launch_bounds__(256) void cvt_kernel(const float* __restrict__ x,
                                                  const float* __restrict__ wq,
                                                  const float* __restrict__ wp,
                                                  const float* __restrict__ size_in,
                                                  const void* __restrict__ mask_raw,
                                                  const int* __restrict__ flags,
                                                  bf16* __restrict__ xb,
                                                  bf16* __restrict__ wqb,
                                                  bf16* __restrict__ wpb,
                                                  float* __restrict__ biasb) {
  const int i = blockIdx.x * 256 + threadIdx.x;  // grid covers 6291456/4
  {
    const float4 v = ((const float4*)x)[i];
    bf16x4 o = {(bf16)v.x, (bf16)v.y, (bf16)v.z, (bf16)v.w};
    ((bf16x4*)xb)[i] = o;
  }
  if (i < 442368) {  // 2304*768/4
    const float4 v = ((const float4*)wq)[i];
    bf16x4 o = {(bf16)v.x, (bf16)v.y, (bf16)v.z, (bf16)v.w};
    ((bf16x4*)wqb)[i] = o;
  }
  if (i < 147456) {  // 768*768/4
    const float4 v = ((const float4*)wp)[i];
    bf16x4 o = {(bf16)v.x, (bf16)v.y, (bf16)v.z, (bf16)v.w};
    ((bf16x4*)wpb)[i] = o;
  }
  if (i < B_ * N_) {
    int mv;
    if (flags[0]) {
      mv = (int)((const unsigned char*)mask_raw)[i];
    } else if (flags[1]) {
      mv = ((const int*)mask_raw)[i];
    } else {  // int64
      const unsigned* m32 = (const unsigned*)mask_raw;
      mv = (int)(m32[2 * i] | m32[2 * i + 1]);
    }
    biasb[i] = mv ? -1e30f : logf(size_in[i]);
  }
}

// ---------------------------------------------------------------------------
// GEMM (NT): out[m][o] = sum_k A[m][k] * W[o][k].  M=8192, K=768.
// MODE 0: scatter epilogue into q[B,H,N,64], k[B,H,N,64], vt[B,H,64,N]
// MODE 1: f32 epilogue outf[m*768+o] = acc + bias[o]
// ---------------------------------------------------------------------------
template <int MODE>
__global__ __launch_bounds__(256) void gemm_bt(const bf16* __restrict__ A,
                                               const bf16* __restrict__ W,
                                               const float* __restrict__ bias,
                                               bf16* __restrict__ out0,
                                               bf16* __restrict__ out1,
                                               bf16* __restrict__ out2,
                                               float* __restrict__ outf) {
  __shared__ bf16 As[128 * 64];
  __shared__ bf16 Bs[128 * 64];
  const int bid = blockIdx.x;
  const int mt = bid % 64;
  const int nt = bid / 64;
  const int t = threadIdx.x;
  const int lane = t & 63, w = t >> 6;
  const int wm = w >> 1, wn = w & 1;
  const int l15 = lane & 15, lg = lane >> 4;

  f32x4 acc[4][4] = {};

  const int srow = t >> 3;
  const int skel = (t & 7) * 8;
  const bf16* Ag = A + (size_t)(mt * 128) * KDIM;
  const bf16* Bg = W + (size_t)(nt * 128) * KDIM;

  for (int kt = 0; kt < KDIM; kt += 64) {
#pragma unroll
    for (int c = 0; c < 4; ++c) {
      gload_lds16(Ag + (size_t)(c * 32 + srow) * KDIM + kt + skel,
                  (char*)As + c * 4096 + w * 1024);
      gload_lds16(Bg + (size_t)(c * 32 + srow) * KDIM + kt + skel,
                  (char*)Bs + c * 4096 + w * 1024);
    }
    __syncthreads();
#pragma unroll
    for (int ks = 0; ks < 2; ++ks) {
      bf16x8 af[4], bfr[4];
#pragma unroll
      for (int i = 0; i < 4; ++i)
        af[i] = *(const bf16x8*)(As + (wm * 64 + i * 16 + l15) * 64 + ks * 32 + lg * 8);
#pragma unroll
      for (int i = 0; i < 4; ++i)
        bfr[i] = *(const bf16x8*)(Bs + (wn * 64 + i * 16 + l15) * 64 + ks * 32 + lg * 8);
#pragma unroll
      for (int i = 0; i < 4; ++i)
#pragma unroll
        for (int j = 0; j < 4; ++j)
          acc[i][j] = MFMA_16x16x32(af[i], bfr[j], acc[i][j]);
    }
    __syncthreads();
  }

  if (MODE == 0) {
    const int which = (nt * 128) / 768;  // 768 = 6*128, tiles never straddle
#pragma unroll
    for (int i = 0; i < 4; ++i)
#pragma unroll
      for (int j = 0; j < 4; ++j)
#pragma unroll
        for (int r = 0; r < 4; ++r) {
          const int m = mt * 128 + wm * 64 + i * 16 + lg * 4 + r;
          const int o = nt * 128 + wn * 64 + j * 16 + l15;
          const int b = m >> 10, n = m & 1023;
          const int f = o - which * 768;
          const int h = f >> 6, hd = f & 63;
          const bf16 bv = (bf16)acc[i][j][r];
          if (which == 0)
            out0[(((size_t)(b * 12 + h)) * 1024 + n) * 64 + hd] = bv;
          else if (which == 1)
            out1[(((size_t)(b * 12 + h)) * 1024 + n) * 64 + hd] = bv;
          else
            out2[(((size_t)(b * 12 + h)) * 64 + hd) * 1024 + n] = bv;
        }
  } else {
#pragma unroll
    for (int i = 0; i < 4; ++i)
#pragma unroll
      for (int j = 0; j < 4; ++j) {
        const int o = nt * 128 + wn * 64 + j * 16 + l15;
        const float bv = bias[o];
#pragma unroll
        for (int r = 0; r < 4; ++r) {
          const int m = mt * 128 + wm * 64 + i * 16 + lg * 4 + r;
          outf[(size_t)m * 768 + o] = acc[i][j][r] + bv;
        }
      }
  }
}

// ---------------------------------------------------------------------------
// k_mean (f32 out): kmean[b,n,hd] = mean_h k[b,h,n,hd]
// ---------------------------------------------------------------------------
__global__ __launch_bounds__(256) void kmean_kernel(const bf16* __restrict__ kbuf,
                                                    float* __restrict__ kmean) {
  const int i = blockIdx.x * 256 + threadIdx.x;
  if (i >= B_ * N_ * HD_) return;
  const int hd = i & 63;
  const int n = (i >> 6) & 1023;
  const int b = i >> 16;
  float s = 0.f;
#pragma unroll
  for (int h = 0; h < 12; ++h)
    s += (float)kbuf[(((size_t)(b * 12 + h)) * 1024 + n) * 64 + hd];
  kmean[i] = s * (1.0f / 12.0f);
}

// ---------------------------------------------------------------------------
// MFMA flash attention, swapped-operand form + LDS double-buffered K/V tiles.
// Block = 8 waves (512 thr, 128 q-rows), KBLK = 64, grid = 8 qt x 96 bh.
// XCD swizzle: id = qt*96 + bh -> XCD = bh%8; each bh's 256KB K/V pins to
// one XCD-L2 (12 bh x 256KB = 3MB < 4MB). Zero dispatch tail (768 = 3/CU).
// K staged pi-permuted (matches swapped-QK frag rows), both tiles bank-
// swizzled slot^=(row&7) via pre-swizzled global source (G21). Softmax is
// lane-local + 2 shuffles; P never leaves the lane.
// ---------------------------------------------------------------------------
__global__ __launch_bounds__(512, 4) void attn_mfma(const bf16* __restrict__ qbuf,
                                                    const bf16* __restrict__ kbuf,
                                                    const bf16* __restrict__ vtbuf,
                                                    const float* __restrict__ biasb,
                                                    bf16* __restrict__ outws) {
  __shared__ bf16 Ks[2][4096];  // [64 rows][8 slots of 8], swizzled
  __shared__ bf16 Vs[2][4096];
  const int id = blockIdx.x;
  const int bh = id % 96;
  const int qt = id / 96;           // 0..7
  const int b = bh / 12, h = bh % 12;
  const int t = threadIdx.x, lane = t & 63, w = t >> 6;  // w 0..7
  const int l15 = lane & 15, lg = lane >> 4;
  const int qbase = qt * 128 + w * 16;

  const bf16* Q = qbuf + ((size_t)bh * 1024 + qbase) * 64;
  const bf16* Kp = kbuf + (size_t)bh * 65536;
  const bf16* Vt = vtbuf + (size_t)bh * 65536;
  const float* bias = biasb + b * 1024;

  // Q as B-operand: col=l15 (q-row), k-slots lg*8+e = d
  const bf16x8 qb0 = *(const bf16x8*)(Q + l15 * 64 + lg * 8);
  const bf16x8 qb1 = *(const bf16x8*)(Q + l15 * 64 + 32 + lg * 8);

  // staging: thread t fills LDS bytes [t*16, t*16+16) of each 8KB tile
  // (wave-uniform base w*1024 + lane*16). Row srow holds key pi(srow) for K,
  // d-row srow for V; phys slot (t&7) holds logical slot dsl = (t&7)^(srow&7).
  const int srow = t >> 3;                 // 0..63
  const int dsl = (t & 7) ^ (srow & 7);
  const int kkey = 32 * ((srow >> 5) & 1) + 4 * ((srow >> 4) & 1) +
                   8 * ((srow >> 2) & 3) + (srow & 3);
  const bf16* srcK = Kp + kkey * 64 + dsl * 8;
  const bf16* srcV = Vt + (size_t)srow * 1024 + dsl * 8;

  gload_lds16(srcK, (char*)&Ks[0][0] + w * 1024);
  gload_lds16(srcV, (char*)&Vs[0][0] + w * 1024);
  __syncthreads();

  const int bb0 = 8 * lg;        // bias quad base (D-row=lg*4+j)
  const int swz = l15 & 7;

  f32x4 oacc[4] = {};
  float m = -1e30f, l = 0.f;

  for (int kt = 0; kt < 16; ++kt) {
    const int cur = kt & 1;
    const int kb = kt * 64;
    if (kt < 15) {  // stage next tile into the other buffer
      gload_lds16(srcK + (size_t)(kb + 64) * 64, (char*)&Ks[cur ^ 1][0] + w * 1024);
      gload_lds16(srcV + (kb + 64), (char*)&Vs[cur ^ 1][0] + w * 1024);
    }

    const bf16* LK = Ks[cur];
    const bf16* LV = Vs[cur];
    float sv[4][4];
#pragma unroll
    for (int f = 0; f < 4; ++f) {
      const int cf = 32 * (f >> 1) + 4 * (f & 1);
      const bf16* kj = LK + (f * 16 + l15) * 64;
      const bf16x8 ka0 = *(const bf16x8*)(kj + (lg ^ swz) * 8);
      const bf16x8 ka1 = *(const bf16x8*)(kj + ((lg + 4) ^ swz) * 8);
      f32x4 z = {};
      z = MFMA_16x16x32(ka0, qb0, z);
      z = MFMA_16x16x32(ka1, qb1, z);
      const float4 bi = *(const float4*)(bias + kb + cf + bb0);
      sv[f][0] = z[0] * 0.125f + bi.x;
      sv[f][1] = z[1] * 0.125f + bi.y;
      sv[f][2] = z[2] * 0.125f + bi.z;
      sv[f][3] = z[3] * 0.125f + bi.w;
    }
    // max over 64 keys for this lane's q=l15: 15 local + 2 shuffles
    float mx = sv[0][0];
#pragma unroll
    for (int f = 0; f < 4; ++f)
#pragma unroll
      for (int j = 0; j < 4; ++j) mx = fmaxf(mx, sv[f][j]);
    mx = fmaxf(mx, __shfl_xor(mx, 16, 64));
    mx = fmaxf(mx, __shfl_xor(mx, 32, 64));
    const float mn = fmaxf(m, mx);
    const float resc = __expf(m - mn);
    m = mn;

    float rs = 0.f;
    bf16x8 pa0, pa1;
#pragma unroll
    for (int f = 0; f < 4; ++f)
#pragma unroll
      for (int j = 0; j < 4; ++j) {
        const float p = __expf(sv[f][j] - mn);
        rs += p;
        const bf16 pb = (bf16)p;
        if (f == 0) pa0[j] = pb;
        else if (f == 1) pa0[4 + j] = pb;
        else if (f == 2) pa1[j] = pb;
        else pa1[4 + j] = pb;
      }
    rs += __shfl_xor(rs, 16, 64);
    rs += __shfl_xor(rs, 32, 64);
    l = l * resc + rs;

#pragma unroll
    for (int df = 0; df < 4; ++df) {
      f32x4 t4 = oacc[df];
#pragma unroll
      for (int j = 0; j < 4; ++j) t4[j] *= resc;
      const bf16* vj = LV + (df * 16 + l15) * 64;
      const bf16x8 va0 = *(const bf16x8*)(vj + (lg ^ swz) * 8);
      const bf16x8 va1 = *(const bf16x8*)(vj + ((lg + 4) ^ swz) * 8);
      t4 = MFMA_16x16x32(va0, pa0, t4);
      t4 = MFMA_16x16x32(va1, pa1, t4);
      oacc[df] = t4;
    }
    __syncthreads();  // drains vmcnt (stage t+1 done); frees buf[cur]
  }

  const float inv = 1.0f / l;
  const size_t orow = ((size_t)b * 1024 + qbase + l15) * 768 + h * 64;
#pragma unroll
  for (int df = 0; df < 4; ++df) {
    bf16x4 ov = {(bf16)(oacc[df][0] * inv), (bf16)(oacc[df][1] * inv),
                 (bf16)(oacc[df][2] * inv), (bf16)(oacc[df][3] * inv)};
    *(bf16x4*)(outws + orow + df * 16 + lg * 4) = ov;
  }
}

// ---------------------------------------------------------------------------
extern "C" void kernel_launch(void* const* d_in, const int* in_sizes, int n_in,
                              void* d_out, int out_size, void* d_ws, size_t ws_size,
                              hipStream_t stream) {
  const float* x       = (const float*)d_in[0];
  const float* size_in = (const float*)d_in[1];
  const void*  mask    = d_in[2];
  const float* w_qkv   = (const float*)d_in[3];
  const float* w_proj  = (const float*)d_in[4];
  const float* b_proj  = (const float*)d_in[5];
  float* out = (float*)d_out;   // f32 outputs per reference dtype

  if (n_in < 6 ||
      in_sizes[0] != 6291456 || in_sizes[1] != 8192 || in_sizes[2] != 8192 ||
      in_sizes[3] != 1769472 || in_sizes[4] != 589824 || in_sizes[5] != 768)
    return;

  const size_t QS = (size_t)B_ * H_ * N_ * HD_;  // 6291456 elems
  if (ws_size < 55083024) return;

  bf16* xb    = (bf16*)d_ws;       // dead after gemm<0>; reused as attnw
  bf16* qbuf  = xb + QS;
  bf16* kbuf  = qbuf + QS;
  bf16* vtbuf = kbuf + QS;
  bf16* wqb   = vtbuf + QS;        // 1769472 elems
  bf16* wpb   = wqb + 1769472;     // 589824 elems
  float* biasb = (float*)(wpb + 589824);
  int* flags = (int*)(biasb + 8192);
  bf16* attnw = xb;

  hipMemsetAsync(flags, 0, 8, stream);
  detect_mask_kernel<<<8, 256, 0, stream>>>((const unsigned*)mask, flags);
  cvt_kernel<<<6144, 256, 0, stream>>>(x, w_qkv, w_proj, size_in, mask, flags,
                                       xb, wqb, wpb, biasb);
  gemm_bt<0><<<64 * 18, 256, 0, stream>>>(xb, wqb, nullptr, qbuf, kbuf, vtbuf, nullptr);
  kmean_kernel<<<2048, 256, 0, stream>>>(kbuf, out + (size_t)B_ * N_ * C_);
  attn_mfma<<<768, 512, 0, stream>>>(qbuf, kbuf, vtbuf, biasb, attnw);
  gemm_bt<1><<<64 * 6, 256, 0, stream>>>(attnw, wpb, b_proj, nullptr, nullptr, nullptr, out);
}